// Round 13
// baseline (1037.813 us; speedup 1.0000x reference)
//
#include <hip/hip_runtime.h>
#include <hip/hip_bf16.h>
#include <hip/hip_cooperative_groups.h>

namespace cg = cooperative_groups;

#define SEQ 2048
#define DM  1024
#define DI  2048
#define DST 16
#define DTR 64
#define NVOC 32000
#define NVOCP 32768   // padded N for lm_head 256-tile grid
#define NC  64    // scan chunks
#define LC  32    // chunk length; NC*LC == SEQ

typedef __bf16 bf16x8 __attribute__((ext_vector_type(8)));
typedef float  f32x4  __attribute__((ext_vector_type(4)));

__device__ __forceinline__ float siluf(float x) { return x / (1.f + expf(-x)); }
__device__ __forceinline__ float softplusf(float x) {
    return fmaxf(x, 0.f) + log1pf(expf(-fabsf(x)));
}
__device__ __forceinline__ unsigned short f2bf(float f) {
    union { __hip_bfloat16 h; unsigned short u; } c;
    c.h = __float2bfloat16(f);
    return c.u;
}

// h[l,:] = embed[ids[l],:]
__global__ void embed_gather(const int* __restrict__ ids, const float* __restrict__ embed,
                             float* __restrict__ h) {
    int l = blockIdx.x;
    int row = ids[l];
    const float4* src = (const float4*)(embed + (size_t)row * DM);
    float4* dst = (float4*)(h + (size_t)l * DM);
    dst[threadIdx.x] = src[threadIdx.x];
}

// o[l,:] = x[l,:]*rsqrt(mean(x^2)+eps)*w[:]
// If ob != nullptr: write ONLY bf16 (f32 skipped). Else write f32.
__global__ void rmsnorm_kernel(const float* __restrict__ x, const float* __restrict__ w,
                               float* __restrict__ o, unsigned short* __restrict__ ob) {
    int l = blockIdx.x;
    int t = threadIdx.x; // 256
    float4 v = ((const float4*)(x + (size_t)l * DM))[t];
    float ss = v.x*v.x + v.y*v.y + v.z*v.z + v.w*v.w;
    #pragma unroll
    for (int m = 32; m; m >>= 1) ss += __shfl_xor(ss, m);
    __shared__ float red[4];
    if ((t & 63) == 0) red[t >> 6] = ss;
    __syncthreads();
    float tot = red[0] + red[1] + red[2] + red[3];
    float sc = rsqrtf(tot * (1.f / DM) + 1e-6f);
    float4 wv = ((const float4*)w)[t];
    float4 ov;
    ov.x = v.x * sc * wv.x;
    ov.y = v.y * sc * wv.y;
    ov.z = v.z * sc * wv.z;
    ov.w = v.w * sc * wv.w;
    if (ob) {
        uint2 pk;
        pk.x = (unsigned)f2bf(ov.x) | ((unsigned)f2bf(ov.y) << 16);
        pk.y = (unsigned)f2bf(ov.z) | ((unsigned)f2bf(ov.w) << 16);
        ((uint2*)(ob + (size_t)l * DM))[t] = pk;
    } else {
        ((float4*)(o + (size_t)l * DM))[t] = ov;
    }
}

// ===== single fused transpose, 64x64 tiles: f32 [K][N] -> bf16 [Npad][K] =====
__global__ void transpose_all(const float* __restrict__ in_w, const float* __restrict__ xp_w,
                              const float* __restrict__ out_w, const float* __restrict__ dt_w,
                              const float* __restrict__ lm_w,
                              unsigned short* __restrict__ in_wT, unsigned short* __restrict__ out_wT,
                              unsigned short* __restrict__ dt_wT, unsigned short* __restrict__ lm_wT) {
    int b = blockIdx.x;
    const float* W; unsigned short* WT; int K, N, Np, loc;
    if      (b < 1024)  { W = in_w;                        WT = in_wT;                                             K=1024; N=4096;  Np=4096;  loc = b; }
    else if (b < 1056)  { W = xp_w;                        WT = in_wT + (size_t)4096 * 1024;                       K=1024; N=96;    Np=128;   loc = b - 1024; }
    else if (b < 2080)  { W = in_w + (size_t)1024 * 4096;  WT = in_wT + (size_t)4224 * 1024;                       K=1024; N=4096;  Np=4096;  loc = b - 1056; }
    else if (b < 2112)  { W = xp_w + (size_t)1024 * 96;    WT = in_wT + (size_t)4224 * 1024 + (size_t)4096 * 1024; K=1024; N=96;    Np=128;   loc = b - 2080; }
    else if (b < 2624)  { W = out_w;                       WT = out_wT;                                            K=2048; N=1024;  Np=1024;  loc = b - 2112; }
    else if (b < 3136)  { W = out_w + (size_t)2048 * 1024; WT = out_wT + (size_t)1024 * 2048;                      K=2048; N=1024;  Np=1024;  loc = b - 2624; }
    else if (b < 3168)  { W = dt_w;                        WT = dt_wT;                                             K=64;   N=2048;  Np=2048;  loc = b - 3136; }
    else if (b < 3200)  { W = dt_w + (size_t)64 * 2048;    WT = dt_wT + (size_t)2048 * 64;                         K=64;   N=2048;  Np=2048;  loc = b - 3168; }
    else                { if (!lm_wT) return; W = lm_w;    WT = lm_wT;                                             K=1024; N=32000; Np=32768; loc = b - 3200; }
    int tiles_x = Np >> 6;
    int n0 = (loc % tiles_x) * 64, k0 = (loc / tiles_x) * 64;
    __shared__ float tile[64][65];   // [n][k]
    int tx = threadIdx.x;  // 32
    int ty = threadIdx.y;  // 8
    #pragma unroll
    for (int i = 0; i < 8; i++) {
        int r = ty + i * 8;                    // k offset
        int n1 = n0 + tx, n2 = n0 + tx + 32;
        tile[tx][r]      = (n1 < N) ? W[(size_t)(k0 + r) * N + n1] : 0.f;
        tile[tx + 32][r] = (n2 < N) ? W[(size_t)(k0 + r) * N + n2] : 0.f;
    }
    __syncthreads();
    int t = ty * 32 + tx;          // 0..255
    int nrow = t >> 5;             // 0..7 (+pass*8)
    int u = t & 31;                // uint index: k = 2u
    #pragma unroll
    for (int pass = 0; pass < 8; pass++) {
        int n = pass * 8 + nrow;
        unsigned v = (unsigned)f2bf(tile[n][2 * u]) | ((unsigned)f2bf(tile[n][2 * u + 1]) << 16);
        *(unsigned*)&WT[(size_t)(n0 + n) * K + k0 + 2 * u] = v;
    }
}

// Generic fp32 GEMM (fallback only)
template<int ACT>
__global__ __launch_bounds__(256) void gemm_f32(const float* __restrict__ A, int lda,
                                                const float* __restrict__ B,
                                                const float* __restrict__ bias,
                                                const float* __restrict__ add,
                                                float* __restrict__ C,
                                                int M, int N, int K) {
    __shared__ float As[16][68];
    __shared__ float Bs[16][64];
    int tx = threadIdx.x, ty = threadIdx.y;
    int t = ty * 16 + tx;
    int m0 = blockIdx.y * 64, n0 = blockIdx.x * 64;
    float acc[4][4] = {};
    for (int k0 = 0; k0 < K; k0 += 16) {
        #pragma unroll
        for (int i = 0; i < 4; i++) {
            int idx = t + i * 256;
            int mm = idx >> 4, kk = idx & 15;
            As[kk][mm] = A[(size_t)(m0 + mm) * lda + k0 + kk];
            int nn = idx & 63, k2 = idx >> 6;
            Bs[k2][nn] = B[(size_t)(k0 + k2) * N + n0 + nn];
        }
        __syncthreads();
        #pragma unroll
        for (int kk = 0; kk < 16; kk++) {
            float4 a = *(const float4*)&As[kk][ty * 4];
            float4 b = *(const float4*)&Bs[kk][tx * 4];
            acc[0][0] += a.x*b.x; acc[0][1] += a.x*b.y; acc[0][2] += a.x*b.z; acc[0][3] += a.x*b.w;
            acc[1][0] += a.y*b.x; acc[1][1] += a.y*b.y; acc[1][2] += a.y*b.z; acc[1][3] += a.y*b.w;
            acc[2][0] += a.z*b.x; acc[2][1] += a.z*b.y; acc[2][2] += a.z*b.z; acc[2][3] += a.z*b.w;
            acc[3][0] += a.w*b.x; acc[3][1] += a.w*b.y; acc[3][2] += a.w*b.z; acc[3][3] += a.w*b.w;
        }
        __syncthreads();
    }
    #pragma unroll
    for (int i = 0; i < 4; i++) {
        int row = m0 + ty * 4 + i;
        float4 r;
        float* pr = &r.x;
        #pragma unroll
        for (int j = 0; j < 4; j++) {
            int col = n0 + tx * 4 + j;
            float v = acc[i][j];
            if (bias) v += bias[col];
            if (add)  v += add[(size_t)row * N + col];
            if (ACT == 1) v = softplusf(v);
            pr[j] = v;
        }
        *(float4*)&C[(size_t)row * N + n0 + tx * 4] = r;
    }
}

// bf16 MFMA GEMM (R3-proven m97 structure): C(MxN,f32) = A(bf16 [M][lda]) @ BT(bf16 [N][K])^T
// 128x128 tile, BK=32, 256 threads = 4 waves (2x2), 4x4 fragments of 16x16x32.
template<int BIAS, int ADD, int ACT, int XP>
__global__ __launch_bounds__(256) void gemm_bf16(const unsigned short* __restrict__ A, int lda,
                                                 const unsigned short* __restrict__ BT,
                                                 const float* __restrict__ bias,
                                                 const float* __restrict__ add,
                                                 float* __restrict__ C,
                                                 float* __restrict__ xp_out,
                                                 unsigned short* __restrict__ aux,
                                                 int M, int N, int K) {
    __shared__ unsigned short As[128 * 32];
    __shared__ unsigned short Bs[128 * 32];
    int t = threadIdx.x;
    int w = t >> 6, l = t & 63;
    int wm = w >> 1, wn = w & 1;
    int m0 = blockIdx.x * 128;
    int n0 = blockIdx.y * 128;
    int lr = l & 15, lk = (l >> 4) * 8;
    int sr = t >> 2, sc = (t & 3) * 8;     // staging: row, k-offset
    f32x4 acc[4][4] = {};
    for (int k0 = 0; k0 < K; k0 += 32) {
        const unsigned short* ga = A  + (size_t)(m0 + sr) * lda + k0 + sc;
        const unsigned short* gb = BT + (size_t)(n0 + sr) * K + k0 + sc;
        unsigned short* la = As + w * 512;   // wave-uniform base; HW adds lane*16B
        unsigned short* lb = Bs + w * 512;
        __builtin_amdgcn_global_load_lds((const __attribute__((address_space(1))) void*)ga,
            (__attribute__((address_space(3))) void*)la, 16, 0, 0);
        __builtin_amdgcn_global_load_lds((const __attribute__((address_space(1))) void*)(ga + (size_t)64 * lda),
            (__attribute__((address_space(3))) void*)(la + 2048), 16, 0, 0);
        __builtin_amdgcn_global_load_lds((const __attribute__((address_space(1))) void*)gb,
            (__attribute__((address_space(3))) void*)(lb), 16, 0, 0);
        __builtin_amdgcn_global_load_lds((const __attribute__((address_space(1))) void*)(gb + (size_t)64 * K),
            (__attribute__((address_space(3))) void*)(lb + 2048), 16, 0, 0);
        __syncthreads();
        bf16x8 af[4], bfr[4];
        #pragma unroll
        for (int i = 0; i < 4; i++) {
            af[i]  = *reinterpret_cast<const bf16x8*>(&As[(wm * 64 + i * 16 + lr) * 32 + lk]);
            bfr[i] = *reinterpret_cast<const bf16x8*>(&Bs[(wn * 64 + i * 16 + lr) * 32 + lk]);
        }
        #pragma unroll
        for (int i = 0; i < 4; i++)
            #pragma unroll
            for (int j = 0; j < 4; j++)
                acc[i][j] = __builtin_amdgcn_mfma_f32_16x16x32_bf16(af[i], bfr[j], acc[i][j], 0, 0, 0);
        __syncthreads();
    }
    int cr = (l >> 4) * 4;
    if (XP && n0 >= 4096) {
        #pragma unroll
        for (int i = 0; i < 4; i++) {
            #pragma unroll
            for (int j = 0; j < 4; j++) {
                int c2 = (n0 - 4096) + wn * 64 + j * 16 + lr;
                #pragma unroll
                for (int rr = 0; rr < 4; rr++) {
                    int row = m0 + wm * 64 + i * 16 + cr + rr;
                    float v = acc[i][j][rr];
                    xp_out[(size_t)row * 128 + c2] = v;
                    if (c2 < 64) aux[(size_t)row * 64 + c2] = f2bf(v);
                }
            }
        }
    } else {
        int ldc = XP ? 4096 : N;
        #pragma unroll
        for (int i = 0; i < 4; i++) {
            #pragma unroll
            for (int j = 0; j < 4; j++) {
                int col = n0 + wn * 64 + j * 16 + lr;
                float bv = BIAS ? bias[col] : 0.f;
                #pragma unroll
                for (int rr = 0; rr < 4; rr++) {
                    int row = m0 + wm * 64 + i * 16 + cr + rr;
                    float v = acc[i][j][rr] + bv;
                    if (ADD) v += add[(size_t)row * ldc + col];
                    if (ACT == 1) v = softplusf(v);
                    C[(size_t)row * ldc + col] = v;
                }
            }
        }
    }
}

// ==== 256x256 lm_head GEMM: 1024 threads (16 waves of 64x64), BK=32, 3-buf ====
// K-loop = R9 body (proven). Epilogue: LDS-staged float4 + NONTEMPORAL stores
// (C is write-once/never-reread: nt keeps 262MB of streaming writes out of L2,
// preserving B-panel residency).
__global__ __launch_bounds__(1024, 4) void gemm_lm(
        const unsigned short* __restrict__ A,
        const unsigned short* __restrict__ BT,
        float* __restrict__ C, int M, int N, int K) {
    extern __shared__ unsigned short lds[];   // 3 x 16384 shorts (A|B per buf)
    const int t = threadIdx.x;
    const int w = t >> 6, l = t & 63;
    const int wr = w >> 2, wc = w & 3;        // 4x4 waves, 64x64 tile each
    int bxx = blockIdx.x, byy = blockIdx.y;
    if (gridDim.x == 8 && (gridDim.y & 7) == 0) {
        int lin = blockIdx.y * 8 + blockIdx.x;
        int xcd = lin & 7, i = lin >> 3;
        bxx = i & 7;
        byy = xcd * (gridDim.y >> 3) + (i >> 3);
    }
    const int m0 = bxx * 256, n0 = byy * 256;
    const int lr = l & 15;
    const int rowA = wr * 64 + lr;
    const int rowB = wc * 64 + lr;
    const int colR = (((l >> 4) ^ (lr & 3)) * 8);   // swizzled ds_read col (shorts)
    const int srow = t >> 2;                        // staging row 0..255
    const int scol = (((t & 3) ^ (srow & 3)) * 8);  // pre-swizzled global col
    const int NT = K >> 5;                          // BK=32
    f32x4 acc[4][4] = {};
    bf16x8 af[4], bf[4];

    const unsigned short* gA = A  + (size_t)(m0 + srow) * K + scol;
    const unsigned short* gB = BT + (size_t)(n0 + srow) * K + scol;

    #pragma unroll
    for (int pp = 0; pp < 2; pp++) {
        if (pp < NT) {
            unsigned short* Ld = lds + pp * 16384;
            __builtin_amdgcn_global_load_lds(
                (const __attribute__((address_space(1))) void*)(gA + pp * 32),
                (__attribute__((address_space(3))) void*)(Ld + w * 512), 16, 0, 0);
            __builtin_amdgcn_global_load_lds(
                (const __attribute__((address_space(1))) void*)(gB + pp * 32),
                (__attribute__((address_space(3))) void*)(Ld + 8192 + w * 512), 16, 0, 0);
        }
    }

    for (int kt = 0; kt < NT; kt++) {
        if (kt >= NT - 2) { asm volatile("s_waitcnt vmcnt(0)" ::: "memory"); }
        else              { asm volatile("s_waitcnt vmcnt(2)" ::: "memory"); }
        __builtin_amdgcn_sched_barrier(0);
        __builtin_amdgcn_s_barrier();
        __builtin_amdgcn_sched_barrier(0);
        const unsigned short* Ab = lds + (kt % 3) * 16384;
        const unsigned short* Bb = Ab + 8192;
        #pragma unroll
        for (int i = 0; i < 4; i++)
            af[i] = *reinterpret_cast<const bf16x8*>(&Ab[(rowA + i * 16) * 32 + colR]);
        #pragma unroll
        for (int j = 0; j < 4; j++)
            bf[j] = *reinterpret_cast<const bf16x8*>(&Bb[(rowB + j * 16) * 32 + colR]);
        if (kt + 2 < NT) {
            unsigned short* Ld = lds + ((kt + 2) % 3) * 16384;
            __builtin_amdgcn_global_load_lds(
                (const __attribute__((address_space(1))) void*)(gA + (kt + 2) * 32),
                (__attribute__((address_space(3))) void*)(Ld + w * 512), 16, 0, 0);
            __builtin_amdgcn_global_load_lds(
                (const __attribute__((address_space(1))) void*)(gB + (kt + 2) * 32),
                (__attribute__((address_space(3))) void*)(Ld + 8192 + w * 512), 16, 0, 0);
        }
        __builtin_amdgcn_s_setprio(1);
        #pragma unroll
        for (int i = 0; i < 4; i++)
            #pragma unroll
            for (int j = 0; j < 4; j++)
                acc[i][j] = __builtin_amdgcn_mfma_f32_16x16x32_bf16(af[i], bf[j], acc[i][j], 0, 0, 0);
        __builtin_amdgcn_s_setprio(0);
    }

    // ---- epilogue: LDS transpose -> f32x4 nontemporal coalesced stores ----
    float* cf = (float*)lds;   // [64][260] f32 = 66.6 KB (fits 96 KB dyn-LDS)
    const int cr = (l >> 4) * 4;
    for (int r = 0; r < 4; r++) {
        __syncthreads();   // previous round's reads complete before overwrite
        if (wr == r) {
            #pragma unroll
            for (int i = 0; i < 4; i++)
                #pragma unroll
                for (int j = 0; j < 4; j++) {
                    int col = wc * 64 + j * 16 + lr;
                    #pragma unroll
                    for (int rr = 0; rr < 4; rr++)
                        cf[(i * 16 + cr + rr) * 260 + col] = acc[i][j][rr];
                }
        }
        __syncthreads();
        #pragma unroll
        for (int pass = 0; pass < 4; pass++) {
            int row = pass * 16 + (t >> 6);
            int f4 = t & 63;
            f32x4 v = *(const f32x4*)&cf[row * 260 + f4 * 4];
            int grow = m0 + r * 64 + row;
            int gcol = n0 + f4 * 4;
            if (gcol < N)
                __builtin_nontemporal_store(v, (f32x4*)&C[(size_t)grow * N + gcol]);
        }
    }
}

// fallback xproj (fp32, stride-128 output)
__global__ void xproj_kernel(const float* __restrict__ u, const float* __restrict__ xw,
                             float* __restrict__ xdbl) {
    int l0 = blockIdx.x * 4;
    int t = threadIdx.x; // 128
    __shared__ float us[4][DM];
    for (int i = t; i < 4 * DM; i += 128) us[i >> 10][i & 1023] = u[(size_t)l0 * DM + i];
    __syncthreads();
    if (t < 96) {
        float a0 = 0.f, a1 = 0.f, a2 = 0.f, a3 = 0.f;
        for (int k = 0; k < DM; k++) {
            float wv = xw[(size_t)k * 96 + t];
            a0 += us[0][k] * wv; a1 += us[1][k] * wv;
            a2 += us[2][k] * wv; a3 += us[3][k] * wv;
        }
        xdbl[(size_t)(l0 + 0) * 128 + t] = a0;
        xdbl[(size_t)(l0 + 1) * 128 + t] = a1;
        xdbl[(size_t)(l0 + 2) * 128 + t] = a2;
        xdbl[(size_t)(l0 + 3) * 128 + t] = a3;
    }
}

// ==== fused selective scan: p1 (local scan) | grid.sync | p2 (compose) |
// grid.sync | p3 (re-run + gate). conv+silu recomputed from xr in p1/p3.
// Grid (NC=64, DI/256=8) = 512 blocks x 256 thr -> 2 blocks/CU co-resident.
__global__ __launch_bounds__(256) void scan_fused(
        const float* __restrict__ xr, const float* __restrict__ delta,
        const float* __restrict__ xdbl, const float* __restrict__ cw,
        const float* __restrict__ cb, const float* __restrict__ A_log,
        const float* __restrict__ Dp,
        float* __restrict__ P, float* __restrict__ S, float* __restrict__ X,
        float* __restrict__ y, unsigned short* __restrict__ yb) {
    cg::grid_group grid = cg::this_grid();
    int c = blockIdx.x;
    int d = blockIdx.y * 256 + threadIdx.x;
    int l0 = c * LC;
    __shared__ float Bsh[LC][16], Csh[LC][16];
    __shared__ float cwsh[4][LC];
    __shared__ float cbsh[LC];
    {
        int t = threadIdx.x;
        #pragma unroll
        for (int i = t; i < LC * 16; i += 256) {
            int ll = i >> 4, q = i & 15;
            size_t row = (size_t)(l0 + ll) * 128;
            Bsh[ll][q] = xdbl[row + 64 + q];
            Csh[ll][q] = xdbl[row + 80 + q];
        }
        if (t < LC) {
            cbsh[t] = cb[l0 + t];
            #pragma unroll
            for (int k = 0; k < 4; k++) cwsh[k][t] = cw[k * SEQ + l0 + t];
        }
    }
    __syncthreads();
    float a[16];
    #pragma unroll
    for (int i = 0; i < 4; i++) {
        float4 al = ((const float4*)(A_log + (size_t)d * 16))[i];
        a[4*i+0] = -expf(al.x); a[4*i+1] = -expf(al.y);
        a[4*i+2] = -expf(al.z); a[4*i+3] = -expf(al.w);
    }
    float Dv = Dp[d];
    size_t o = ((size_t)c * DI + d) * 16;

    // ---- p1: local scan from zero state ----
    {
        float s[16] = {};
        float sumdv = 0.f;
        for (int ll = 0; ll < LC; ll++) {
            size_t lrow = (size_t)(l0 + ll);
            float dv = delta[lrow * DI + d];
            const float* xrow = xr + lrow * 4096;
            float accv = cbsh[ll];
            #pragma unroll
            for (int k = 0; k < 4; k++) {
                int cc = d + k - 1;
                if (cc >= 0 && cc < DI) accv += xrow[cc] * cwsh[k][ll];
            }
            float xv = siluf(accv);
            float du = dv * xv;
            sumdv += dv;
            #pragma unroll
            for (int n = 0; n < 16; n++)
                s[n] = expf(dv * a[n]) * s[n] + du * Bsh[ll][n];
        }
        #pragma unroll
        for (int i = 0; i < 4; i++) {
            float4 sv = make_float4(s[4*i], s[4*i+1], s[4*i+2], s[4*i+3]);
            float4 pv = make_float4(expf(a[4*i]*sumdv), expf(a[4*i+1]*sumdv),
                                    expf(a[4*i+2]*sumdv), expf(a[4*i+3]*sumdv));
            ((float4*)(S + o))[i] = sv;
            ((float4*)(P + o))[i] = pv;
        }
    }
    grid.sync();
    // ---- p2: serial chunk composition (first 128 blocks) ----
    {
        int lin = blockIdx.y * gridDim.x + blockIdx.x;
        if (lin < (DI * 16) / 256) {
            int t2 = lin * 256 + threadIdx.x;
            float x = 0.f;
            #pragma unroll 16
            for (int cc = 0; cc < NC; cc++) {
                X[(size_t)cc * (DI * 16) + t2] = x;
                x = P[(size_t)cc * (DI * 16) + t2] * x + S[(size_t)cc * (DI * 16) + t2];
            }
        }
    }
    grid.sync();
    // ---- p3: re-run from true initial state; silu(res) gate fused ----
    {
        float s[16];
        #pragma unroll
        for (int i = 0; i < 4; i++) {
            float4 xv4 = ((const float4*)(X + o))[i];
            s[4*i] = xv4.x; s[4*i+1] = xv4.y; s[4*i+2] = xv4.z; s[4*i+3] = xv4.w;
        }
        for (int ll = 0; ll < LC; ll++) {
            size_t lrow = (size_t)(l0 + ll);
            float dv = delta[lrow * DI + d];
            const float* xrow = xr + lrow * 4096;
            float accv = cbsh[ll];
            #pragma unroll
            for (int k = 0; k < 4; k++) {
                int cc = d + k - 1;
                if (cc >= 0 && cc < DI) accv += xrow[cc] * cwsh[k][ll];
            }
            float xv = siluf(accv);
            float du = dv * xv;
            float yv = 0.f;
            #pragma unroll
            for (int n = 0; n < 16; n++) {
                s[n] = expf(dv * a[n]) * s[n] + du * Bsh[ll][n];
                yv += s[n] * Csh[ll][n];
            }
            float res = xrow[2048 + d];
            float val = (yv + xv * Dv) * siluf(res);
            if (yb) yb[lrow * DI + d] = f2bf(val);
            else    y[lrow * DI + d] = val;
        }
    }
}

extern "C" void kernel_launch(void* const* d_in, const int* in_sizes, int n_in,
                              void* d_out, int out_size, void* d_ws, size_t ws_size,
                              hipStream_t stream) {
    const int*   ids        = (const int*)d_in[0];
    const float* embed      = (const float*)d_in[1];
    const float* norm_scale = (const float*)d_in[2];
    const float* in_w       = (const float*)d_in[3];
    const float* in_b       = (const float*)d_in[4];
    const float* conv_w     = (const float*)d_in[5];
    const float* conv_b     = (const float*)d_in[6];
    const float* x_proj_w   = (const float*)d_in[7];
    const float* dt_w       = (const float*)d_in[8];
    const float* dt_b       = (const float*)d_in[9];
    const float* out_w      = (const float*)d_in[10];
    const float* out_b      = (const float*)d_in[11];
    const float* A_log      = (const float*)d_in[12];
    const float* Dp         = (const float*)d_in[13];
    const float* norm_f     = (const float*)d_in[14];
    const float* lm_w       = (const float*)d_in[15];

    float* out = (float*)d_out;

    // ---- workspace layout ----
    char* p = (char*)d_ws;
    float* h  = (float*)p;  p += (size_t)SEQ * DM * 4;
    float* hn = (float*)p;  p += (size_t)SEQ * DM * 4;
    size_t base = (size_t)p - (size_t)d_ws;
    const size_t SZ_UB    = (size_t)SEQ * DM * 2;
    const size_t SZ_YB    = (size_t)SEQ * DI * 2;
    const size_t SZ_HNB   = (size_t)SEQ * DM * 2;
    const size_t SZ_DB    = (size_t)SEQ * 64 * 2;
    const size_t SZ_INWT  = (size_t)2 * 4224 * DM * 2;   // in_proj(4096) + xproj(128) rows
    const size_t SZ_OUTWT = (size_t)2 * DM * DI * 2;
    const size_t SZ_DTWT  = (size_t)2 * DI * 64 * 2;
    const size_t SZ_LMWT  = (size_t)NVOCP * DM * 2;      // padded to 32768 rows
    size_t need_mid  = base + SZ_UB + SZ_YB + SZ_HNB + SZ_DB + SZ_INWT + SZ_OUTWT + SZ_DTWT;
    size_t need_full = need_mid + SZ_LMWT;
    bool mid  = ws_size >= need_mid;
    bool full = ws_size >= need_full;

    unsigned short *u_b = nullptr, *y_b = nullptr, *hn_b = nullptr, *dlt_b = nullptr;
    unsigned short *in_wT = nullptr, *out_wT = nullptr, *dt_wT = nullptr, *lm_wT = nullptr;
    if (mid) {
        u_b    = (unsigned short*)p; p += SZ_UB;
        y_b    = (unsigned short*)p; p += SZ_YB;
        hn_b   = (unsigned short*)p; p += SZ_HNB;
        dlt_b  = (unsigned short*)p; p += SZ_DB;
        in_wT  = (unsigned short*)p; p += SZ_INWT;
        out_wT = (unsigned short*)p; p += SZ_OUTWT;
        dt_wT  = (unsigned short*)p; p += SZ_DTWT;
        if (full) { lm_wT = (unsigned short*)p; p += SZ_LMWT; }
    }

    // transient scratch inside d_out (fully rewritten by final GEMM)
    float* u     = out;                          // SEQ*DM (fallback only)
    float* xr    = u + (size_t)SEQ * DM;         // SEQ*4096
    float* xdbl  = xr + (size_t)SEQ * 4096;      // SEQ*128
    float* delta = xdbl + (size_t)SEQ * 128;     // SEQ*DI
    float* y     = delta + (size_t)SEQ * DI;     // SEQ*DI (fallback only)
    float* Pbuf  = y + (size_t)SEQ * DI;         // NC*DI*16
    float* Sbuf  = Pbuf + (size_t)NC * DI * 16;  // NC*DI*16
    float* Xbuf  = Sbuf + (size_t)NC * DI * 16;  // NC*DI*16

    // ---- weight convert+transpose: ONE kernel (64x64 tiles) ----
    if (mid) {
        int nblocks = full ? 11392 : 3200;
        transpose_all<<<nblocks, dim3(32, 8), 0, stream>>>(
            in_w, x_proj_w, out_w, dt_w, lm_w, in_wT, out_wT, dt_wT, lm_wT);
    }

    embed_gather<<<SEQ, 256, 0, stream>>>(ids, embed, h);

    for (int L = 0; L < 2; L++) {
        rmsnorm_kernel<<<SEQ, 256, 0, stream>>>(h, norm_scale + (size_t)L * DM, u, u_b);
        if (mid) {
            // fused in_proj + xproj: N = 4224 (33 tiles); cols>=4096 -> xdbl/dlt_b
            gemm_bf16<1, 0, 0, 1><<<dim3(SEQ / 128, 4224 / 128), 256, 0, stream>>>(
                u_b, DM, in_wT + (size_t)L * 4224 * DM, in_b + (size_t)L * 4096, nullptr, xr,
                xdbl, dlt_b, SEQ, 4224, DM);
            gemm_bf16<1, 0, 1, 0><<<dim3(SEQ / 128, DI / 128), 256, 0, stream>>>(
                dlt_b, 64, dt_wT + (size_t)L * DI * 64, dt_b + (size_t)L * DI, nullptr, delta,
                nullptr, nullptr, SEQ, DI, 64);
        } else {
            gemm_f32<0><<<dim3(4096 / 64, SEQ / 64), dim3(16, 16), 0, stream>>>(
                u, DM, in_w + (size_t)L * DM * 4096, in_b + (size_t)L * 4096, nullptr, xr,
                SEQ, 4096, DM);
            xproj_kernel<<<SEQ / 4, 128, 0, stream>>>(u, x_proj_w + (size_t)L * DM * 96, xdbl);
            gemm_f32<1><<<dim3(DI / 64, SEQ / 64), dim3(16, 16), 0, stream>>>(
                xdbl, 128, dt_w + (size_t)L * DTR * DI, dt_b + (size_t)L * DI, nullptr, delta,
                SEQ, DI, DTR);
        }
        {
            const float* cwp = conv_w + (size_t)L * 4 * SEQ;
            const float* cbp = conv_b + (size_t)L * SEQ;
            const float* alp = A_log + (size_t)L * DI * DST;
            const float* dpp = Dp + (size_t)L * DI;
            const float* xrp = xr;
            const float* dlp = delta;
            const float* xdp = xdbl;
            float* yp = y;
            unsigned short* ybp = y_b;
            float* Pp = Pbuf; float* Sp = Sbuf; float* Xp = Xbuf;
            void* kargs[] = {(void*)&xrp, (void*)&dlp, (void*)&xdp, (void*)&cwp,
                             (void*)&cbp, (void*)&alp, (void*)&dpp,
                             (void*)&Pp, (void*)&Sp, (void*)&Xp,
                             (void*)&yp, (void*)&ybp};
            (void)hipLaunchCooperativeKernel((const void*)scan_fused, dim3(NC, DI / 256),
                                             dim3(256), kargs, 0, stream);
        }
        if (mid) {
            gemm_bf16<1, 1, 0, 0><<<dim3(SEQ / 128, DM / 128), 256, 0, stream>>>(
                y_b, DI, out_wT + (size_t)L * DM * DI, out_b + (size_t)L * DM, h, h,
                nullptr, nullptr, SEQ, DM, DI);
        } else {
            gemm_f32<0><<<dim3(DM / 64, SEQ / 64), dim3(16, 16), 0, stream>>>(
                y, DI, out_w + (size_t)L * DI * DM, out_b + (size_t)L * DM, h, h,
                SEQ, DM, DI);
        }
    }

    rmsnorm_kernel<<<SEQ, 256, 0, stream>>>(h, norm_f, hn, full ? hn_b : nullptr);
    if (full) {
        (void)hipFuncSetAttribute((const void*)gemm_lm,
                                  hipFuncAttributeMaxDynamicSharedMemorySize, 98304);
        gemm_lm<<<dim3(SEQ / 256, NVOCP / 256), 1024, 98304, stream>>>(
            hn_b, lm_wT, out, SEQ, NVOC, DM);
    } else {
        gemm_f32<0><<<dim3(NVOC / 64, SEQ / 64), dim3(16, 16), 0, stream>>>(
            hn, DM, lm_w, nullptr, nullptr, out, SEQ, NVOC, DM);
    }
}

// Round 14
// 770.671 us; speedup vs baseline: 1.3466x; 1.3466x over previous
//
#include <hip/hip_runtime.h>
#include <hip/hip_bf16.h>

#define SEQ 2048
#define DM  1024
#define DI  2048
#define DST 16
#define DTR 64
#define NVOC 32000
#define NVOCP 32768   // padded N for lm_head 256-tile grid
#define NC  64    // scan chunks
#define LC  32    // chunk length; NC*LC == SEQ

typedef __bf16 bf16x8 __attribute__((ext_vector_type(8)));
typedef float  f32x4  __attribute__((ext_vector_type(4)));

__device__ __forceinline__ float siluf(float x) { return x / (1.f + expf(-x)); }
__device__ __forceinline__ float softplusf(float x) {
    return fmaxf(x, 0.f) + log1pf(expf(-fabsf(x)));
}
__device__ __forceinline__ unsigned short f2bf(float f) {
    union { __hip_bfloat16 h; unsigned short u; } c;
    c.h = __float2bfloat16(f);
    return c.u;
}

// h[l,:] = embed[ids[l],:]
__global__ void embed_gather(const int* __restrict__ ids, const float* __restrict__ embed,
                             float* __restrict__ h) {
    int l = blockIdx.x;
    int row = ids[l];
    const float4* src = (const float4*)(embed + (size_t)row * DM);
    float4* dst = (float4*)(h + (size_t)l * DM);
    dst[threadIdx.x] = src[threadIdx.x];
}

// o[l,:] = x[l,:]*rsqrt(mean(x^2)+eps)*w[:]
// If ob != nullptr: write ONLY bf16 (f32 skipped). Else write f32.
__global__ void rmsnorm_kernel(const float* __restrict__ x, const float* __restrict__ w,
                               float* __restrict__ o, unsigned short* __restrict__ ob) {
    int l = blockIdx.x;
    int t = threadIdx.x; // 256
    float4 v = ((const float4*)(x + (size_t)l * DM))[t];
    float ss = v.x*v.x + v.y*v.y + v.z*v.z + v.w*v.w;
    #pragma unroll
    for (int m = 32; m; m >>= 1) ss += __shfl_xor(ss, m);
    __shared__ float red[4];
    if ((t & 63) == 0) red[t >> 6] = ss;
    __syncthreads();
    float tot = red[0] + red[1] + red[2] + red[3];
    float sc = rsqrtf(tot * (1.f / DM) + 1e-6f);
    float4 wv = ((const float4*)w)[t];
    float4 ov;
    ov.x = v.x * sc * wv.x;
    ov.y = v.y * sc * wv.y;
    ov.z = v.z * sc * wv.z;
    ov.w = v.w * sc * wv.w;
    if (ob) {
        uint2 pk;
        pk.x = (unsigned)f2bf(ov.x) | ((unsigned)f2bf(ov.y) << 16);
        pk.y = (unsigned)f2bf(ov.z) | ((unsigned)f2bf(ov.w) << 16);
        ((uint2*)(ob + (size_t)l * DM))[t] = pk;
    } else {
        ((float4*)(o + (size_t)l * DM))[t] = ov;
    }
}

// ===== single fused transpose, 64x64 tiles: f32 [K][N] -> bf16 [Npad][K] =====
__global__ void transpose_all(const float* __restrict__ in_w, const float* __restrict__ xp_w,
                              const float* __restrict__ out_w, const float* __restrict__ dt_w,
                              const float* __restrict__ lm_w,
                              unsigned short* __restrict__ in_wT, unsigned short* __restrict__ out_wT,
                              unsigned short* __restrict__ dt_wT, unsigned short* __restrict__ lm_wT) {
    int b = blockIdx.x;
    const float* W; unsigned short* WT; int K, N, Np, loc;
    if      (b < 1024)  { W = in_w;                        WT = in_wT;                                             K=1024; N=4096;  Np=4096;  loc = b; }
    else if (b < 1056)  { W = xp_w;                        WT = in_wT + (size_t)4096 * 1024;                       K=1024; N=96;    Np=128;   loc = b - 1024; }
    else if (b < 2080)  { W = in_w + (size_t)1024 * 4096;  WT = in_wT + (size_t)4224 * 1024;                       K=1024; N=4096;  Np=4096;  loc = b - 1056; }
    else if (b < 2112)  { W = xp_w + (size_t)1024 * 96;    WT = in_wT + (size_t)4224 * 1024 + (size_t)4096 * 1024; K=1024; N=96;    Np=128;   loc = b - 2080; }
    else if (b < 2624)  { W = out_w;                       WT = out_wT;                                            K=2048; N=1024;  Np=1024;  loc = b - 2112; }
    else if (b < 3136)  { W = out_w + (size_t)2048 * 1024; WT = out_wT + (size_t)1024 * 2048;                      K=2048; N=1024;  Np=1024;  loc = b - 2624; }
    else if (b < 3168)  { W = dt_w;                        WT = dt_wT;                                             K=64;   N=2048;  Np=2048;  loc = b - 3136; }
    else if (b < 3200)  { W = dt_w + (size_t)64 * 2048;    WT = dt_wT + (size_t)2048 * 64;                         K=64;   N=2048;  Np=2048;  loc = b - 3168; }
    else                { if (!lm_wT) return; W = lm_w;    WT = lm_wT;                                             K=1024; N=32000; Np=32768; loc = b - 3200; }
    int tiles_x = Np >> 6;
    int n0 = (loc % tiles_x) * 64, k0 = (loc / tiles_x) * 64;
    __shared__ float tile[64][65];   // [n][k]
    int tx = threadIdx.x;  // 32
    int ty = threadIdx.y;  // 8
    #pragma unroll
    for (int i = 0; i < 8; i++) {
        int r = ty + i * 8;                    // k offset
        int n1 = n0 + tx, n2 = n0 + tx + 32;
        tile[tx][r]      = (n1 < N) ? W[(size_t)(k0 + r) * N + n1] : 0.f;
        tile[tx + 32][r] = (n2 < N) ? W[(size_t)(k0 + r) * N + n2] : 0.f;
    }
    __syncthreads();
    int t = ty * 32 + tx;          // 0..255
    int nrow = t >> 5;             // 0..7 (+pass*8)
    int u = t & 31;                // uint index: k = 2u
    #pragma unroll
    for (int pass = 0; pass < 8; pass++) {
        int n = pass * 8 + nrow;
        unsigned v = (unsigned)f2bf(tile[n][2 * u]) | ((unsigned)f2bf(tile[n][2 * u + 1]) << 16);
        *(unsigned*)&WT[(size_t)(n0 + n) * K + k0 + 2 * u] = v;
    }
}

// Generic fp32 GEMM (fallback only)
template<int ACT>
__global__ __launch_bounds__(256) void gemm_f32(const float* __restrict__ A, int lda,
                                                const float* __restrict__ B,
                                                const float* __restrict__ bias,
                                                const float* __restrict__ add,
                                                float* __restrict__ C,
                                                int M, int N, int K) {
    __shared__ float As[16][68];
    __shared__ float Bs[16][64];
    int tx = threadIdx.x, ty = threadIdx.y;
    int t = ty * 16 + tx;
    int m0 = blockIdx.y * 64, n0 = blockIdx.x * 64;
    float acc[4][4] = {};
    for (int k0 = 0; k0 < K; k0 += 16) {
        #pragma unroll
        for (int i = 0; i < 4; i++) {
            int idx = t + i * 256;
            int mm = idx >> 4, kk = idx & 15;
            As[kk][mm] = A[(size_t)(m0 + mm) * lda + k0 + kk];
            int nn = idx & 63, k2 = idx >> 6;
            Bs[k2][nn] = B[(size_t)(k0 + k2) * N + n0 + nn];
        }
        __syncthreads();
        #pragma unroll
        for (int kk = 0; kk < 16; kk++) {
            float4 a = *(const float4*)&As[kk][ty * 4];
            float4 b = *(const float4*)&Bs[kk][tx * 4];
            acc[0][0] += a.x*b.x; acc[0][1] += a.x*b.y; acc[0][2] += a.x*b.z; acc[0][3] += a.x*b.w;
            acc[1][0] += a.y*b.x; acc[1][1] += a.y*b.y; acc[1][2] += a.y*b.z; acc[1][3] += a.y*b.w;
            acc[2][0] += a.z*b.x; acc[2][1] += a.z*b.y; acc[2][2] += a.z*b.z; acc[2][3] += a.z*b.w;
            acc[3][0] += a.w*b.x; acc[3][1] += a.w*b.y; acc[3][2] += a.w*b.z; acc[3][3] += a.w*b.w;
        }
        __syncthreads();
    }
    #pragma unroll
    for (int i = 0; i < 4; i++) {
        int row = m0 + ty * 4 + i;
        float4 r;
        float* pr = &r.x;
        #pragma unroll
        for (int j = 0; j < 4; j++) {
            int col = n0 + tx * 4 + j;
            float v = acc[i][j];
            if (bias) v += bias[col];
            if (add)  v += add[(size_t)row * N + col];
            if (ACT == 1) v = softplusf(v);
            pr[j] = v;
        }
        *(float4*)&C[(size_t)row * N + n0 + tx * 4] = r;
    }
}

// bf16 MFMA GEMM (R3-proven m97 structure): C(MxN,f32) = A(bf16 [M][lda]) @ BT(bf16 [N][K])^T
// 128x128 tile, BK=32, 256 threads = 4 waves (2x2), 4x4 fragments of 16x16x32.
template<int BIAS, int ADD, int ACT, int XP>
__global__ __launch_bounds__(256) void gemm_bf16(const unsigned short* __restrict__ A, int lda,
                                                 const unsigned short* __restrict__ BT,
                                                 const float* __restrict__ bias,
                                                 const float* __restrict__ add,
                                                 float* __restrict__ C,
                                                 float* __restrict__ xp_out,
                                                 unsigned short* __restrict__ aux,
                                                 int M, int N, int K) {
    __shared__ unsigned short As[128 * 32];
    __shared__ unsigned short Bs[128 * 32];
    int t = threadIdx.x;
    int w = t >> 6, l = t & 63;
    int wm = w >> 1, wn = w & 1;
    int m0 = blockIdx.x * 128;
    int n0 = blockIdx.y * 128;
    int lr = l & 15, lk = (l >> 4) * 8;
    int sr = t >> 2, sc = (t & 3) * 8;     // staging: row, k-offset
    f32x4 acc[4][4] = {};
    for (int k0 = 0; k0 < K; k0 += 32) {
        const unsigned short* ga = A  + (size_t)(m0 + sr) * lda + k0 + sc;
        const unsigned short* gb = BT + (size_t)(n0 + sr) * K + k0 + sc;
        unsigned short* la = As + w * 512;   // wave-uniform base; HW adds lane*16B
        unsigned short* lb = Bs + w * 512;
        __builtin_amdgcn_global_load_lds((const __attribute__((address_space(1))) void*)ga,
            (__attribute__((address_space(3))) void*)la, 16, 0, 0);
        __builtin_amdgcn_global_load_lds((const __attribute__((address_space(1))) void*)(ga + (size_t)64 * lda),
            (__attribute__((address_space(3))) void*)(la + 2048), 16, 0, 0);
        __builtin_amdgcn_global_load_lds((const __attribute__((address_space(1))) void*)gb,
            (__attribute__((address_space(3))) void*)(lb), 16, 0, 0);
        __builtin_amdgcn_global_load_lds((const __attribute__((address_space(1))) void*)(gb + (size_t)64 * K),
            (__attribute__((address_space(3))) void*)(lb + 2048), 16, 0, 0);
        __syncthreads();
        bf16x8 af[4], bfr[4];
        #pragma unroll
        for (int i = 0; i < 4; i++) {
            af[i]  = *reinterpret_cast<const bf16x8*>(&As[(wm * 64 + i * 16 + lr) * 32 + lk]);
            bfr[i] = *reinterpret_cast<const bf16x8*>(&Bs[(wn * 64 + i * 16 + lr) * 32 + lk]);
        }
        #pragma unroll
        for (int i = 0; i < 4; i++)
            #pragma unroll
            for (int j = 0; j < 4; j++)
                acc[i][j] = __builtin_amdgcn_mfma_f32_16x16x32_bf16(af[i], bfr[j], acc[i][j], 0, 0, 0);
        __syncthreads();
    }
    int cr = (l >> 4) * 4;
    if (XP && n0 >= 4096) {
        #pragma unroll
        for (int i = 0; i < 4; i++) {
            #pragma unroll
            for (int j = 0; j < 4; j++) {
                int c2 = (n0 - 4096) + wn * 64 + j * 16 + lr;
                #pragma unroll
                for (int rr = 0; rr < 4; rr++) {
                    int row = m0 + wm * 64 + i * 16 + cr + rr;
                    float v = acc[i][j][rr];
                    xp_out[(size_t)row * 128 + c2] = v;
                    if (c2 < 64) aux[(size_t)row * 64 + c2] = f2bf(v);
                }
            }
        }
    } else {
        int ldc = XP ? 4096 : N;
        #pragma unroll
        for (int i = 0; i < 4; i++) {
            #pragma unroll
            for (int j = 0; j < 4; j++) {
                int col = n0 + wn * 64 + j * 16 + lr;
                float bv = BIAS ? bias[col] : 0.f;
                #pragma unroll
                for (int rr = 0; rr < 4; rr++) {
                    int row = m0 + wm * 64 + i * 16 + cr + rr;
                    float v = acc[i][j][rr] + bv;
                    if (ADD) v += add[(size_t)row * ldc + col];
                    if (ACT == 1) v = softplusf(v);
                    C[(size_t)row * ldc + col] = v;
                }
            }
        }
    }
}

// ==== 256x256 lm_head GEMM: 1024 threads (16 waves of 64x64), BK=32, 3-buf ====
// K-loop = R9 body (proven). Epilogue: LDS-staged f32x4 + NONTEMPORAL stores.
__global__ __launch_bounds__(1024, 4) void gemm_lm(
        const unsigned short* __restrict__ A,
        const unsigned short* __restrict__ BT,
        float* __restrict__ C, int M, int N, int K) {
    extern __shared__ unsigned short lds[];   // 3 x 16384 shorts (A|B per buf)
    const int t = threadIdx.x;
    const int w = t >> 6, l = t & 63;
    const int wr = w >> 2, wc = w & 3;        // 4x4 waves, 64x64 tile each
    int bxx = blockIdx.x, byy = blockIdx.y;
    if (gridDim.x == 8 && (gridDim.y & 7) == 0) {
        int lin = blockIdx.y * 8 + blockIdx.x;
        int xcd = lin & 7, i = lin >> 3;
        bxx = i & 7;
        byy = xcd * (gridDim.y >> 3) + (i >> 3);
    }
    const int m0 = bxx * 256, n0 = byy * 256;
    const int lr = l & 15;
    const int rowA = wr * 64 + lr;
    const int rowB = wc * 64 + lr;
    const int colR = (((l >> 4) ^ (lr & 3)) * 8);   // swizzled ds_read col (shorts)
    const int srow = t >> 2;                        // staging row 0..255
    const int scol = (((t & 3) ^ (srow & 3)) * 8);  // pre-swizzled global col
    const int NT = K >> 5;                          // BK=32
    f32x4 acc[4][4] = {};
    bf16x8 af[4], bf[4];

    const unsigned short* gA = A  + (size_t)(m0 + srow) * K + scol;
    const unsigned short* gB = BT + (size_t)(n0 + srow) * K + scol;

    #pragma unroll
    for (int pp = 0; pp < 2; pp++) {
        if (pp < NT) {
            unsigned short* Ld = lds + pp * 16384;
            __builtin_amdgcn_global_load_lds(
                (const __attribute__((address_space(1))) void*)(gA + pp * 32),
                (__attribute__((address_space(3))) void*)(Ld + w * 512), 16, 0, 0);
            __builtin_amdgcn_global_load_lds(
                (const __attribute__((address_space(1))) void*)(gB + pp * 32),
                (__attribute__((address_space(3))) void*)(Ld + 8192 + w * 512), 16, 0, 0);
        }
    }

    for (int kt = 0; kt < NT; kt++) {
        if (kt >= NT - 2) { asm volatile("s_waitcnt vmcnt(0)" ::: "memory"); }
        else              { asm volatile("s_waitcnt vmcnt(2)" ::: "memory"); }
        __builtin_amdgcn_sched_barrier(0);
        __builtin_amdgcn_s_barrier();
        __builtin_amdgcn_sched_barrier(0);
        const unsigned short* Ab = lds + (kt % 3) * 16384;
        const unsigned short* Bb = Ab + 8192;
        #pragma unroll
        for (int i = 0; i < 4; i++)
            af[i] = *reinterpret_cast<const bf16x8*>(&Ab[(rowA + i * 16) * 32 + colR]);
        #pragma unroll
        for (int j = 0; j < 4; j++)
            bf[j] = *reinterpret_cast<const bf16x8*>(&Bb[(rowB + j * 16) * 32 + colR]);
        if (kt + 2 < NT) {
            unsigned short* Ld = lds + ((kt + 2) % 3) * 16384;
            __builtin_amdgcn_global_load_lds(
                (const __attribute__((address_space(1))) void*)(gA + (kt + 2) * 32),
                (__attribute__((address_space(3))) void*)(Ld + w * 512), 16, 0, 0);
            __builtin_amdgcn_global_load_lds(
                (const __attribute__((address_space(1))) void*)(gB + (kt + 2) * 32),
                (__attribute__((address_space(3))) void*)(Ld + 8192 + w * 512), 16, 0, 0);
        }
        __builtin_amdgcn_s_setprio(1);
        #pragma unroll
        for (int i = 0; i < 4; i++)
            #pragma unroll
            for (int j = 0; j < 4; j++)
                acc[i][j] = __builtin_amdgcn_mfma_f32_16x16x32_bf16(af[i], bf[j], acc[i][j], 0, 0, 0);
        __builtin_amdgcn_s_setprio(0);
    }

    // ---- epilogue: LDS transpose -> f32x4 nontemporal coalesced stores ----
    float* cf = (float*)lds;   // [64][260] f32 = 66.6 KB (fits 96 KB dyn-LDS)
    const int cr = (l >> 4) * 4;
    for (int r = 0; r < 4; r++) {
        __syncthreads();   // previous round's reads complete before overwrite
        if (wr == r) {
            #pragma unroll
            for (int i = 0; i < 4; i++)
                #pragma unroll
                for (int j = 0; j < 4; j++) {
                    int col = wc * 64 + j * 16 + lr;
                    #pragma unroll
                    for (int rr = 0; rr < 4; rr++)
                        cf[(i * 16 + cr + rr) * 260 + col] = acc[i][j][rr];
                }
        }
        __syncthreads();
        #pragma unroll
        for (int pass = 0; pass < 4; pass++) {
            int row = pass * 16 + (t >> 6);
            int f4 = t & 63;
            f32x4 v = *(const f32x4*)&cf[row * 260 + f4 * 4];
            int grow = m0 + r * 64 + row;
            int gcol = n0 + f4 * 4;
            if (gcol < N)
                __builtin_nontemporal_store(v, (f32x4*)&C[(size_t)grow * N + gcol]);
        }
    }
}

// fallback xproj (fp32, stride-128 output)
__global__ void xproj_kernel(const float* __restrict__ u, const float* __restrict__ xw,
                             float* __restrict__ xdbl) {
    int l0 = blockIdx.x * 4;
    int t = threadIdx.x; // 128
    __shared__ float us[4][DM];
    for (int i = t; i < 4 * DM; i += 128) us[i >> 10][i & 1023] = u[(size_t)l0 * DM + i];
    __syncthreads();
    if (t < 96) {
        float a0 = 0.f, a1 = 0.f, a2 = 0.f, a3 = 0.f;
        for (int k = 0; k < DM; k++) {
            float wv = xw[(size_t)k * 96 + t];
            a0 += us[0][k] * wv; a1 += us[1][k] * wv;
            a2 += us[2][k] * wv; a3 += us[3][k] * wv;
        }
        xdbl[(size_t)(l0 + 0) * 128 + t] = a0;
        xdbl[(size_t)(l0 + 1) * 128 + t] = a1;
        xdbl[(size_t)(l0 + 2) * 128 + t] = a2;
        xdbl[(size_t)(l0 + 3) * 128 + t] = a3;
    }
}

// ---- chunked selective scan with fused conv+silu (x = silu(conv(xr))) ----
__global__ __launch_bounds__(256) void scan_p1(const float* __restrict__ xr,
        const float* __restrict__ delta, const float* __restrict__ xdbl,
        const float* __restrict__ cw, const float* __restrict__ cb,
        const float* __restrict__ A_log, float* __restrict__ P, float* __restrict__ S) {
    int c = blockIdx.x;
    int d = blockIdx.y * 256 + threadIdx.x;
    int l0 = c * LC;
    __shared__ float Bsh[LC][16];
    __shared__ float cwsh[4][LC];
    __shared__ float cbsh[LC];
    {
        int t = threadIdx.x;
        #pragma unroll
        for (int i = t; i < LC * 16; i += 256) {
            int ll = i >> 4, q = i & 15;
            Bsh[ll][q] = xdbl[(size_t)(l0 + ll) * 128 + 64 + q];
        }
        if (t < LC) {
            cbsh[t] = cb[l0 + t];
            #pragma unroll
            for (int k = 0; k < 4; k++) cwsh[k][t] = cw[k * SEQ + l0 + t];
        }
    }
    __syncthreads();
    float a[16];
    #pragma unroll
    for (int i = 0; i < 4; i++) {
        float4 al = ((const float4*)(A_log + (size_t)d * 16))[i];
        a[4*i+0] = -expf(al.x); a[4*i+1] = -expf(al.y);
        a[4*i+2] = -expf(al.z); a[4*i+3] = -expf(al.w);
    }
    float s[16] = {};
    float sumdv = 0.f;
    for (int ll = 0; ll < LC; ll++) {
        size_t lrow = (size_t)(l0 + ll);
        float dv = delta[lrow * DI + d];
        const float* xrow = xr + lrow * 4096;
        float accv = cbsh[ll];
        #pragma unroll
        for (int k = 0; k < 4; k++) {
            int cc = d + k - 1;
            if (cc >= 0 && cc < DI) accv += xrow[cc] * cwsh[k][ll];
        }
        float xv = siluf(accv);
        float du = dv * xv;
        sumdv += dv;
        #pragma unroll
        for (int n = 0; n < 16; n++)
            s[n] = expf(dv * a[n]) * s[n] + du * Bsh[ll][n];
    }
    size_t o = ((size_t)c * DI + d) * 16;
    #pragma unroll
    for (int i = 0; i < 4; i++) {
        float4 sv = make_float4(s[4*i], s[4*i+1], s[4*i+2], s[4*i+3]);
        float4 pv = make_float4(expf(a[4*i]*sumdv), expf(a[4*i+1]*sumdv),
                                expf(a[4*i+2]*sumdv), expf(a[4*i+3]*sumdv));
        ((float4*)(S + o))[i] = sv;
        ((float4*)(P + o))[i] = pv;
    }
}

// Pass 2: compose chunk states serially: X[c] = state entering chunk c
__global__ void scan_p2(const float* __restrict__ P, const float* __restrict__ S,
                        float* __restrict__ X) {
    int t = blockIdx.x * 256 + threadIdx.x;   // 0 .. DI*16-1
    float x = 0.f;
    #pragma unroll 16
    for (int c = 0; c < NC; c++) {
        X[(size_t)c * (DI*16) + t] = x;
        x = P[(size_t)c * (DI*16) + t] * x + S[(size_t)c * (DI*16) + t];
    }
}

// Pass 3: re-run chunk from true initial state; always applies silu(res) gate.
__global__ __launch_bounds__(256) void scan_p3(const float* __restrict__ xr,
        const float* __restrict__ delta, const float* __restrict__ xdbl,
        const float* __restrict__ cw, const float* __restrict__ cb,
        const float* __restrict__ A_log, const float* __restrict__ Dp,
        const float* __restrict__ X,
        float* __restrict__ y, unsigned short* __restrict__ yb) {
    int c = blockIdx.x;
    int d = blockIdx.y * 256 + threadIdx.x;
    int l0 = c * LC;
    __shared__ float Bsh[LC][16], Csh[LC][16];
    __shared__ float cwsh[4][LC];
    __shared__ float cbsh[LC];
    {
        int t = threadIdx.x;
        #pragma unroll
        for (int i = t; i < LC * 16; i += 256) {
            int ll = i >> 4, q = i & 15;
            size_t row = (size_t)(l0 + ll) * 128;
            Bsh[ll][q] = xdbl[row + 64 + q];
            Csh[ll][q] = xdbl[row + 80 + q];
        }
        if (t < LC) {
            cbsh[t] = cb[l0 + t];
            #pragma unroll
            for (int k = 0; k < 4; k++) cwsh[k][t] = cw[k * SEQ + l0 + t];
        }
    }
    __syncthreads();
    float a[16];
    #pragma unroll
    for (int i = 0; i < 4; i++) {
        float4 al = ((const float4*)(A_log + (size_t)d * 16))[i];
        a[4*i+0] = -expf(al.x); a[4*i+1] = -expf(al.y);
        a[4*i+2] = -expf(al.z); a[4*i+3] = -expf(al.w);
    }
    float s[16];
    size_t o = ((size_t)c * DI + d) * 16;
    #pragma unroll
    for (int i = 0; i < 4; i++) {
        float4 xv4 = ((const float4*)(X + o))[i];
        s[4*i] = xv4.x; s[4*i+1] = xv4.y; s[4*i+2] = xv4.z; s[4*i+3] = xv4.w;
    }
    float Dv = Dp[d];
    for (int ll = 0; ll < LC; ll++) {
        size_t lrow = (size_t)(l0 + ll);
        float dv = delta[lrow * DI + d];
        const float* xrow = xr + lrow * 4096;
        float accv = cbsh[ll];
        #pragma unroll
        for (int k = 0; k < 4; k++) {
            int cc = d + k - 1;
            if (cc >= 0 && cc < DI) accv += xrow[cc] * cwsh[k][ll];
        }
        float xv = siluf(accv);
        float du = dv * xv;
        float yv = 0.f;
        #pragma unroll
        for (int n = 0; n < 16; n++) {
            s[n] = expf(dv * a[n]) * s[n] + du * Bsh[ll][n];
            yv += s[n] * Csh[ll][n];
        }
        float res = xrow[2048 + d];
        float val = (yv + xv * Dv) * siluf(res);
        if (yb) yb[lrow * DI + d] = f2bf(val);
        else    y[lrow * DI + d] = val;
    }
}

extern "C" void kernel_launch(void* const* d_in, const int* in_sizes, int n_in,
                              void* d_out, int out_size, void* d_ws, size_t ws_size,
                              hipStream_t stream) {
    const int*   ids        = (const int*)d_in[0];
    const float* embed      = (const float*)d_in[1];
    const float* norm_scale = (const float*)d_in[2];
    const float* in_w       = (const float*)d_in[3];
    const float* in_b       = (const float*)d_in[4];
    const float* conv_w     = (const float*)d_in[5];
    const float* conv_b     = (const float*)d_in[6];
    const float* x_proj_w   = (const float*)d_in[7];
    const float* dt_w       = (const float*)d_in[8];
    const float* dt_b       = (const float*)d_in[9];
    const float* out_w      = (const float*)d_in[10];
    const float* out_b      = (const float*)d_in[11];
    const float* A_log      = (const float*)d_in[12];
    const float* Dp         = (const float*)d_in[13];
    const float* norm_f     = (const float*)d_in[14];
    const float* lm_w       = (const float*)d_in[15];

    float* out = (float*)d_out;

    // ---- workspace layout ----
    char* p = (char*)d_ws;
    float* h  = (float*)p;  p += (size_t)SEQ * DM * 4;
    float* hn = (float*)p;  p += (size_t)SEQ * DM * 4;
    size_t base = (size_t)p - (size_t)d_ws;
    const size_t SZ_UB    = (size_t)SEQ * DM * 2;
    const size_t SZ_YB    = (size_t)SEQ * DI * 2;
    const size_t SZ_HNB   = (size_t)SEQ * DM * 2;
    const size_t SZ_DB    = (size_t)SEQ * 64 * 2;
    const size_t SZ_INWT  = (size_t)2 * 4224 * DM * 2;   // in_proj(4096) + xproj(128) rows
    const size_t SZ_OUTWT = (size_t)2 * DM * DI * 2;
    const size_t SZ_DTWT  = (size_t)2 * DI * 64 * 2;
    const size_t SZ_LMWT  = (size_t)NVOCP * DM * 2;      // padded to 32768 rows
    size_t need_mid  = base + SZ_UB + SZ_YB + SZ_HNB + SZ_DB + SZ_INWT + SZ_OUTWT + SZ_DTWT;
    size_t need_full = need_mid + SZ_LMWT;
    bool mid  = ws_size >= need_mid;
    bool full = ws_size >= need_full;

    unsigned short *u_b = nullptr, *y_b = nullptr, *hn_b = nullptr, *dlt_b = nullptr;
    unsigned short *in_wT = nullptr, *out_wT = nullptr, *dt_wT = nullptr, *lm_wT = nullptr;
    if (mid) {
        u_b    = (unsigned short*)p; p += SZ_UB;
        y_b    = (unsigned short*)p; p += SZ_YB;
        hn_b   = (unsigned short*)p; p += SZ_HNB;
        dlt_b  = (unsigned short*)p; p += SZ_DB;
        in_wT  = (unsigned short*)p; p += SZ_INWT;
        out_wT = (unsigned short*)p; p += SZ_OUTWT;
        dt_wT  = (unsigned short*)p; p += SZ_DTWT;
        if (full) { lm_wT = (unsigned short*)p; p += SZ_LMWT; }
    }

    // transient scratch inside d_out (fully rewritten by final GEMM)
    float* u     = out;                          // SEQ*DM (fallback only)
    float* xr    = u + (size_t)SEQ * DM;         // SEQ*4096
    float* xdbl  = xr + (size_t)SEQ * 4096;      // SEQ*128
    float* delta = xdbl + (size_t)SEQ * 128;     // SEQ*DI
    float* y     = delta + (size_t)SEQ * DI;     // SEQ*DI (fallback only)
    float* Pbuf  = y + (size_t)SEQ * DI;         // NC*DI*16
    float* Sbuf  = Pbuf + (size_t)NC * DI * 16;  // NC*DI*16
    float* Xbuf  = Sbuf + (size_t)NC * DI * 16;  // NC*DI*16

    // ---- weight convert+transpose: ONE kernel (64x64 tiles) ----
    if (mid) {
        int nblocks = full ? 11392 : 3200;
        transpose_all<<<nblocks, dim3(32, 8), 0, stream>>>(
            in_w, x_proj_w, out_w, dt_w, lm_w, in_wT, out_wT, dt_wT, lm_wT);
    }

    embed_gather<<<SEQ, 256, 0, stream>>>(ids, embed, h);

    for (int L = 0; L < 2; L++) {
        rmsnorm_kernel<<<SEQ, 256, 0, stream>>>(h, norm_scale + (size_t)L * DM, u, u_b);
        if (mid) {
            // fused in_proj + xproj: N = 4224 (33 tiles); cols>=4096 -> xdbl/dlt_b
            gemm_bf16<1, 0, 0, 1><<<dim3(SEQ / 128, 4224 / 128), 256, 0, stream>>>(
                u_b, DM, in_wT + (size_t)L * 4224 * DM, in_b + (size_t)L * 4096, nullptr, xr,
                xdbl, dlt_b, SEQ, 4224, DM);
            gemm_bf16<1, 0, 1, 0><<<dim3(SEQ / 128, DI / 128), 256, 0, stream>>>(
                dlt_b, 64, dt_wT + (size_t)L * DI * 64, dt_b + (size_t)L * DI, nullptr, delta,
                nullptr, nullptr, SEQ, DI, 64);
        } else {
            gemm_f32<0><<<dim3(4096 / 64, SEQ / 64), dim3(16, 16), 0, stream>>>(
                u, DM, in_w + (size_t)L * DM * 4096, in_b + (size_t)L * 4096, nullptr, xr,
                SEQ, 4096, DM);
            xproj_kernel<<<SEQ / 4, 128, 0, stream>>>(u, x_proj_w + (size_t)L * DM * 96, xdbl);
            gemm_f32<1><<<dim3(DI / 64, SEQ / 64), dim3(16, 16), 0, stream>>>(
                xdbl, 128, dt_w + (size_t)L * DTR * DI, dt_b + (size_t)L * DI, nullptr, delta,
                SEQ, DI, DTR);
        }
        scan_p1<<<dim3(NC, DI / 256), 256, 0, stream>>>(
            xr, delta, xdbl, conv_w + (size_t)L * 4 * SEQ, conv_b + (size_t)L * SEQ,
            A_log + (size_t)L * DI * DST, Pbuf, Sbuf);
        scan_p2<<<DI * 16 / 256, 256, 0, stream>>>(Pbuf, Sbuf, Xbuf);
        scan_p3<<<dim3(NC, DI / 256), 256, 0, stream>>>(
            xr, delta, xdbl, conv_w + (size_t)L * 4 * SEQ, conv_b + (size_t)L * SEQ,
            A_log + (size_t)L * DI * DST, Dp + (size_t)L * DI, Xbuf, y, y_b);
        if (mid) {
            gemm_bf16<1, 1, 0, 0><<<dim3(SEQ / 128, DM / 128), 256, 0, stream>>>(
                y_b, DI, out_wT + (size_t)L * DM * DI, out_b + (size_t)L * DM, h, h,
                nullptr, nullptr, SEQ, DM, DI);
        } else {
            gemm_f32<0><<<dim3(DM / 64, SEQ / 64), dim3(16, 16), 0, stream>>>(
                y, DI, out_w + (size_t)L * DI * DM, out_b + (size_t)L * DM, h, h,
                SEQ, DM, DI);
        }
    }

    rmsnorm_kernel<<<SEQ, 256, 0, stream>>>(h, norm_f, hn, full ? hn_b : nullptr);
    if (full) {
        (void)hipFuncSetAttribute((const void*)gemm_lm,
                                  hipFuncAttributeMaxDynamicSharedMemorySize, 98304);
        gemm_lm<<<dim3(SEQ / 256, NVOCP / 256), 1024, 98304, stream>>>(
            hn_b, lm_wT, out, SEQ, NVOC, DM);
    } else {
        gemm_f32<0><<<dim3(NVOC / 64, SEQ / 64), dim3(16, 16), 0, stream>>>(
            hn, DM, lm_w, nullptr, nullptr, out, SEQ, NVOC, DM);
    }
}